// Round 9
// baseline (12152.683 us; speedup 1.0000x reference)
//
#include <hip/hip_runtime.h>

// Hierarchical RNN — wave-autonomous dataflow, v9.
// One wave owns (d, 8 b-rows, 8 n). No __syncthreads in the time loop:
// m-reduction by __shfl_xor butterfly, finalize in-wave (lanes mseg<2),
// per-producer-wave tags, store-only WAR read-flags with ring-4 slack.
// Blocks only share LDS weights per (d, nt); padded layout = conflict-free.

#define TSTEPS 512
#define BATCH  128
#define DMOD   3
#define NH     512
#define CCLS   2
#define NTHR   256
#define NBLK   768
#define OUT2   (DMOD * BATCH * NH)
#define WSTRIDE 516          // floats per mseg block: 64*8 + 4 pad (bank spread)

typedef unsigned long long u64;
typedef unsigned int u32;
typedef float v2f __attribute__((ext_vector_type(2)));

__device__ __forceinline__ float bflo(u32 u) { return __uint_as_float(u << 16); }
__device__ __forceinline__ float bfhi(u32 u) { return __uint_as_float(u & 0xffff0000u); }
__device__ __forceinline__ unsigned short f2bf(float x) {
    u32 u = __float_as_uint(x);
    return (unsigned short)((u + 0x7fffu + ((u >> 16) & 1u)) >> 16);
}
__device__ __forceinline__ u64 pack4bf(float a, float b, float c, float d) {
    u32 lo = (u32)f2bf(a) | ((u32)f2bf(b) << 16);
    u32 hi = (u32)f2bf(c) | ((u32)f2bf(d) << 16);
    return (u64)lo | ((u64)hi << 32);
}
__device__ __forceinline__ float lrelu(float x) { return fmaxf(x, 0.01f * x); }

__device__ __forceinline__ u64 ld_h(const u64* p) {
    return __hip_atomic_load(p, __ATOMIC_RELAXED, __HIP_MEMORY_SCOPE_AGENT);
}
__device__ __forceinline__ void st_h(u64* p, u64 v) {
    __hip_atomic_store(p, v, __ATOMIC_RELAXED, __HIP_MEMORY_SCOPE_AGENT);
}
__device__ __forceinline__ u32 ld_tag(const u32* p) {
    return __hip_atomic_load(p, __ATOMIC_RELAXED, __HIP_MEMORY_SCOPE_AGENT);
}
__device__ __forceinline__ void st_tag(u32* p, u32 v) {
    __hip_atomic_store(p, v, __ATOMIC_RELAXED, __HIP_MEMORY_SCOPE_AGENT);
}
__device__ __forceinline__ int ld_slot(const int* p) {
    return __hip_atomic_load(p, __ATOMIC_RELAXED, __HIP_MEMORY_SCOPE_AGENT);
}
__device__ __forceinline__ void st_slot(int* p, int v) {
    __hip_atomic_store(p, v, __ATOMIC_RELAXED, __HIP_MEMORY_SCOPE_AGENT);
}

#define PK4(H, WP, OFF) { v2f h2_ = {(H), (H)}; \
    acc0 += h2_ * WP[(OFF) + 0]; acc1 += h2_ * WP[(OFF) + 1]; \
    acc2 += h2_ * WP[(OFF) + 2]; acc3 += h2_ * WP[(OFF) + 3]; }

#define PKU64(U, WP, I) { \
    PK4(bflo((u32)(U)),         WP, ((I) * 4 + 0) * 4) \
    PK4(bfhi((u32)(U)),         WP, ((I) * 4 + 1) * 4) \
    PK4(bflo((u32)((U) >> 32)), WP, ((I) * 4 + 2) * 4) \
    PK4(bfhi((u32)((U) >> 32)), WP, ((I) * 4 + 3) * 4) }

__global__ __launch_bounds__(NTHR, 3)
void rnn_v9(const float* __restrict__ data,
            const float* __restrict__ h0,
            const float* __restrict__ W_in,
            const float* __restrict__ b_in,
            const float* __restrict__ W_hh,
            const float* __restrict__ b_hh,
            const float* __restrict__ W_ff,
            const float* __restrict__ b_ff,
            const float* __restrict__ taus,
            const float* __restrict__ W_fc,
            const float* __restrict__ b_fc,
            float* __restrict__ out,
            int* __restrict__ wsI)
{
    __shared__ float s_whh[8 * WSTRIDE];   // 16.5 KB, [mseg][64 m][8 n]+pad
    __shared__ float s_wff[8 * WSTRIDE];   // 16.5 KB

    const int tid  = threadIdx.x;
    const int blk  = blockIdx.x;
    const int d    = blk >> 8;
    const int r    = blk & 255;
    const int nt   = r >> 2;              // 0..63
    const int q    = r & 3;
    const int wave = tid >> 6;
    const int lane = tid & 63;
    const int mseg = lane >> 3;           // 0..7
    const int b    = lane & 7;            // 0..7
    const int cb   = q * 4 + wave;        // 0..15 row-tile
    const int row  = cb * 8 + b;          // 0..127
    const int n0   = nt * 8;
    const int coh  = d * 16 + cb;         // cohort 0..47

    // ws: tags[4][48][64] u32 @0 (48KB); rdfl[48][64] int @49152; hb @65536
    u32* tags = (u32*)wsI;
    int* rdfl = wsI + 12288;
    u64* hbq  = (u64*)((char*)wsI + 65536);   // slab(s,d,cb)=((s*3+d)*16+cb)*1024 u64

    // ---- stage weights: [mseg][mi][nl], transposed, diag zeroed ----
    {
        const float* gw = W_hh + (size_t)d * NH * NH;
        const float* gf = (d > 0) ? (W_ff + (size_t)(d - 1) * NH * NH) : nullptr;
        for (int idx = tid; idx < 4096; idx += NTHR) {
            int nl = idx & 7, mi = (idx >> 3) & 63, ms = idx >> 9;
            int m = ms * 64 + mi, n = n0 + nl;
            float v = gw[(size_t)n * NH + m];
            if (n == m) v = 0.0f;
            s_whh[ms * WSTRIDE + mi * 8 + nl] = v;
            if (d > 0) s_wff[ms * WSTRIDE + mi * 8 + nl] = gf[(size_t)n * NH + m];
        }
    }
    __syncthreads();   // the ONLY block-wide sync

    const v2f* wpO = (const v2f*)s_whh + (size_t)mseg * (WSTRIDE / 2);
    const v2f* wpF = (const v2f*)s_wff + (size_t)mseg * (WSTRIDE / 2);
    const int goff = 8 * mseg + b;                     // u64 units, +64*i
    const int soff = ((2 * nt + mseg) & 15) * 64 + (nt >> 3) * 8 + b;  // mseg<2

    // finalize constants (lanes mseg<2 only; nh = mseg)
    float winp[4], cbias[4], al[4], itau[4];
    u64 prev = 0;
    if (lane < 16) {
#pragma unroll
        for (int j = 0; j < 4; ++j) {
            int n = n0 + mseg * 4 + j;
            winp[j] = W_in[d * NH + n];
            float cb2 = b_hh[d * NH + n] + b_in[d * NH + n];
            if (d > 0) cb2 += b_ff[(d - 1) * NH + n];
            cbias[j] = cb2;
            float tc = fmaxf(taus[d * NH + n], 1.0f);
            itau[j]  = 1.0f / tc;
            al[j]    = 1.0f - itau[j];
        }
    }

    for (int t = 0; t < TSTEPS; ++t) {
        float xs = 0.0f;
        if (lane < 16) xs = data[t * BATCH + row];

        // ---- dependency spin: 64 lanes x 64 producer tags, one __all ----
        if (t > 0 || d > 0) {
            const u32* ta = tags + ((size_t)((t - 1) & 3) * 48 + coh) * 64 + lane;
            const u32* tf = tags + ((size_t)(t & 3) * 48 + (coh - 16)) * 64 + lane;
            const bool nO = (t > 0), nF = (d > 0);
            while (1) {
                bool ok = true;
                if (nO) ok = (ld_tag(ta) == (u32)t);
                if (nF) ok = ok && (ld_tag(tf) == (u32)(t + 1));
                if (__all(ok)) break;
                __builtin_amdgcn_s_sleep(1);
            }
            asm volatile("" ::: "memory");
        }

        // ---- matmul: each lane 64 m x 8 n (own + ff) ----
        v2f acc0 = {0, 0}, acc1 = {0, 0}, acc2 = {0, 0}, acc3 = {0, 0};

        u64 gu[16];
        if (d > 0) {
            const u64* fg = hbq + ((size_t)((t & 3) * 3 + (d - 1)) * 16 + cb) * 1024 + goff;
#pragma unroll
            for (int i = 0; i < 16; ++i) gu[i] = ld_h(fg + 64 * i);
        }
        if (t == 0) {
            const float4* h4 = (const float4*)h0 + (size_t)(d * BATCH + row) * 128 + mseg * 16;
            float4 hv[16];
#pragma unroll
            for (int i = 0; i < 16; ++i) hv[i] = h4[i];
#pragma unroll
            for (int i = 0; i < 16; ++i) {
                PK4(hv[i].x, wpO, (i * 4 + 0) * 4)
                PK4(hv[i].y, wpO, (i * 4 + 1) * 4)
                PK4(hv[i].z, wpO, (i * 4 + 2) * 4)
                PK4(hv[i].w, wpO, (i * 4 + 3) * 4)
            }
        } else {
            const u64* og = hbq + ((size_t)(((t - 1) & 3) * 3 + d) * 16 + cb) * 1024 + goff;
            u64 hu[16];
#pragma unroll
            for (int i = 0; i < 16; ++i) hu[i] = ld_h(og + 64 * i);
#pragma unroll
            for (int i = 0; i < 16; ++i) { PKU64(hu[i], wpO, i) }
        }
        if (d > 0) {
#pragma unroll
            for (int i = 0; i < 16; ++i) { PKU64(gu[i], wpF, i) }
        }

        // ---- in-wave butterfly reduction over mseg (lane bits 3..5) ----
        float a[8] = {acc0.x, acc0.y, acc1.x, acc1.y, acc2.x, acc2.y, acc3.x, acc3.y};
#pragma unroll
        for (int k = 0; k < 8; ++k) {
            a[k] += __shfl_xor(a[k], 8, 64);
            a[k] += __shfl_xor(a[k], 16, 64);
            a[k] += __shfl_xor(a[k], 32, 64);
        }

        // ---- publish read progress, then WAR guard (ring-4 slack) ----
        if (lane == 0) st_slot(rdfl + coh * 64 + nt, t);
        if (t >= 4) {
            const int* ro = rdfl + coh * 64 + lane;
            const int* ru = rdfl + (coh + 16) * 64 + lane;   // valid iff d<2
            while (1) {
                bool ok = (ld_slot(ro) >= t - 3);
                if (d < DMOD - 1) ok = ok && (ld_slot(ru) >= t - 4);
                if (__all(ok)) break;
                __builtin_amdgcn_s_sleep(1);
            }
        }

        // ---- finalize: lanes mseg<2, 4 n each; store 8B granule ----
        if (lane < 16) {
            float h0f, h1f, h2f, h3f;
            if (t == 0) {
                float4 v = *(const float4*)(h0 + (size_t)(d * BATCH + row) * NH
                                            + n0 + mseg * 4);
                h0f = v.x; h1f = v.y; h2f = v.z; h3f = v.w;
            } else {
                h0f = bflo((u32)prev);         h1f = bfhi((u32)prev);
                h2f = bflo((u32)(prev >> 32)); h3f = bfhi((u32)(prev >> 32));
            }
            float p0 = a[mseg * 4 + 0] + cbias[0] + xs * winp[0];
            float p1 = a[mseg * 4 + 1] + cbias[1] + xs * winp[1];
            float p2 = a[mseg * 4 + 2] + cbias[2] + xs * winp[2];
            float p3 = a[mseg * 4 + 3] + cbias[3] + xs * winp[3];
            float n0v = al[0] * h0f + lrelu(p0) * itau[0];
            float n1v = al[1] * h1f + lrelu(p1) * itau[1];
            float n2v = al[2] * h2f + lrelu(p2) * itau[2];
            float n3v = al[3] * h3f + lrelu(p3) * itau[3];
            u64 pk = pack4bf(n0v, n1v, n2v, n3v);
            st_h(hbq + ((size_t)((t & 3) * 3 + d) * 16 + cb) * 1024 + soff, pk);
            prev = pk;
            if (t == TSTEPS - 1) {
                *(float4*)(out + (size_t)(d * BATCH + row) * NH + n0 + mseg * 4)
                    = make_float4(n0v, n1v, n2v, n3v);
            }
        }
        __threadfence_block();   // wave-level vmcnt drain: payload acked
        if (lane == 0) {
            st_tag(tags + ((size_t)(t & 3) * 48 + coh) * 64 + nt, (u32)(t + 1));
        }
    }

    // ---- readout heads: waves nt<2, c=nt, 8 rows each ----
    if (nt < CCLS) {
        const int c = nt;
        const u32* tf2 = tags + ((size_t)3 * 48 + coh) * 64 + lane;
        while (!__all(ld_tag(tf2) == (u32)TSTEPS)) __builtin_amdgcn_s_sleep(2);
        asm volatile("" ::: "memory");
        const u64* hf = hbq + ((size_t)(3 * 3 + d) * 16 + cb) * 1024 + goff;
        const float4* wf = (const float4*)(W_fc + (size_t)(d * CCLS + c) * NH) + mseg * 16;
        float dotv = 0.0f;
#pragma unroll
        for (int i = 0; i < 16; ++i) {
            u64 u = ld_h(hf + 64 * i);
            float4 w = wf[i];
            dotv += bflo((u32)u) * w.x + bfhi((u32)u) * w.y
                  + bflo((u32)(u >> 32)) * w.z + bfhi((u32)(u >> 32)) * w.w;
        }
        dotv += __shfl_xor(dotv, 8, 64);
        dotv += __shfl_xor(dotv, 16, 64);
        dotv += __shfl_xor(dotv, 32, 64);
        if (mseg == 0) {
            out[OUT2 + (size_t)(d * BATCH + row) * CCLS + c] = dotv + b_fc[d * CCLS + c];
        }
    }
}

extern "C" void kernel_launch(void* const* d_in, const int* in_sizes, int n_in,
                              void* d_out, int out_size, void* d_ws, size_t ws_size,
                              hipStream_t stream) {
    const float* data = (const float*)d_in[0];
    const float* h0   = (const float*)d_in[1];
    const float* W_in = (const float*)d_in[2];
    const float* b_in = (const float*)d_in[3];
    const float* W_hh = (const float*)d_in[4];
    const float* b_hh = (const float*)d_in[5];
    const float* W_ff = (const float*)d_in[6];
    const float* b_ff = (const float*)d_in[7];
    const float* taus = (const float*)d_in[8];
    const float* W_fc = (const float*)d_in[9];
    const float* b_fc = (const float*)d_in[10];

    // no init: tag poison 0xAAAAAAAA != 1..512; rdfl poison negative = "not
    // done". Store-only flags, no RMW.
    hipLaunchKernelGGL(rnn_v9, dim3(NBLK), dim3(NTHR), 0, stream,
                       data, h0, W_in, b_in, W_hh, b_hh, W_ff, b_ff,
                       taus, W_fc, b_fc, (float*)d_out, (int*)d_ws);
}

// Round 10
// 10632.763 us; speedup vs baseline: 1.1429x; 1.1429x over previous
//
#include <hip/hip_runtime.h>

// Hierarchical RNN — dataflow persistent kernel, v10.
// v6 skeleton (designated pollers, 2 barriers/step, store-only flags,
// ring-4 coalesced bf16 h slabs) with NT 8->16: halves the h-exchange
// read volume (41 -> 20.5 MB/step) and the producer fan-in (64 -> 32).
// Weights fp32 in LDS = exactly 64 KB; in-wave butterfly m-reduction
// (no s_red, finalize distributed across all 4 waves); weight rows
// quad-rotated so 8 mseg readers hit disjoint bank groups.

#define TSTEPS 512
#define BATCH  128
#define DMOD   3
#define NH     512
#define CCLS   2

#define BT     32
#define NT     16
#define NTHR   256
#define NBLK   (DMOD * (BATCH / BT) * (NH / NT))   // 3*4*32 = 384
#define RING   4
#define OUT2   (DMOD * BATCH * NH)

typedef unsigned long long u64;
typedef unsigned int u32;
typedef float v2f __attribute__((ext_vector_type(2)));

__device__ __forceinline__ float bflo(u32 u) { return __uint_as_float(u << 16); }
__device__ __forceinline__ float bfhi(u32 u) { return __uint_as_float(u & 0xffff0000u); }
__device__ __forceinline__ unsigned short f2bf(float x) {
    u32 u = __float_as_uint(x);
    return (unsigned short)((u + 0x7fffu + ((u >> 16) & 1u)) >> 16);
}
__device__ __forceinline__ u64 pack4bf(float a, float b, float c, float d) {
    u32 lo = (u32)f2bf(a) | ((u32)f2bf(b) << 16);
    u32 hi = (u32)f2bf(c) | ((u32)f2bf(d) << 16);
    return (u64)lo | ((u64)hi << 32);
}
__device__ __forceinline__ float lrelu(float x) { return fmaxf(x, 0.01f * x); }

__device__ __forceinline__ u64 ld_h(const u64* p) {
    return __hip_atomic_load(p, __ATOMIC_RELAXED, __HIP_MEMORY_SCOPE_AGENT);
}
__device__ __forceinline__ void st_h(u64* p, u64 v) {
    __hip_atomic_store(p, v, __ATOMIC_RELAXED, __HIP_MEMORY_SCOPE_AGENT);
}
__device__ __forceinline__ int ld_slot(const int* p) {
    return __hip_atomic_load(p, __ATOMIC_RELAXED, __HIP_MEMORY_SCOPE_AGENT);
}
__device__ __forceinline__ void st_slot(int* p, int v) {
    __hip_atomic_store(p, v, __ATOMIC_RELAXED, __HIP_MEMORY_SCOPE_AGENT);
}

// One m-row: read 4 quad-rotated float4 weight groups, FMA into 8 v2f accs.
#define MR4(H, SW, M) { \
    const float* rw_ = (SW) + (M) * NT; \
    float h_ = (H); v2f h2_ = {h_, h_}; \
    _Pragma("unroll") \
    for (int q_ = 0; q_ < 4; ++q_) { \
        int p_ = (q_ + rot) & 3; \
        float4 w_ = *(const float4*)(rw_ + p_ * 4); \
        acc[q_ * 2]     += h2_ * (v2f){w_.x, w_.y}; \
        acc[q_ * 2 + 1] += h2_ * (v2f){w_.z, w_.w}; \
    } }

__global__ __launch_bounds__(NTHR, 2)
void rnn_v10(const float* __restrict__ data,
             const float* __restrict__ h0,
             const float* __restrict__ W_in,
             const float* __restrict__ b_in,
             const float* __restrict__ W_hh,
             const float* __restrict__ b_hh,
             const float* __restrict__ W_ff,
             const float* __restrict__ b_ff,
             const float* __restrict__ taus,
             const float* __restrict__ W_fc,
             const float* __restrict__ b_fc,
             float* __restrict__ out,
             int* __restrict__ wsI)
{
    __shared__ float s_whh[NH * NT];   // 32 KB, quad-rotated rows
    __shared__ float s_wff[NH * NT];   // 32 KB  (total exactly 64 KB)

    const int tid = threadIdx.x;
    const int blk = blockIdx.x;
    const int d   = blk >> 7;          // 128 blocks per module
    const int rem = blk & 127;
    const int bt  = rem >> 5;          // 0..3
    const int nt  = rem & 31;          // 0..31
    const int b0  = bt * BT;
    const int n0  = nt * NT;
    const int g   = d * 4 + bt;        // group 0..11

    int* slots = wsI;                              // 12 groups x 32 dense ints
    u64* hbq   = (u64*)((char*)wsI + 65536);       // [4][12][128 mg][32 row] u64

    // ---- stage weights, transposed, quad-rotated: row m quad qn at (qn+(m>>6))&3
    {
        const float* gw = W_hh + (size_t)d * NH * NH;
        for (int idx = tid; idx < NH * NT; idx += NTHR) {
            int nl = idx >> 9;             // 0..15
            int m  = idx & (NH - 1);       // coalesced
            int n  = n0 + nl;
            float v = gw[(size_t)n * NH + m];
            if (n == m) v = 0.0f;
            int pos = ((((nl >> 2) + (m >> 6)) & 3) << 2) | (nl & 3);
            s_whh[m * NT + pos] = v;
        }
        if (d > 0) {
            const float* gf = W_ff + (size_t)(d - 1) * NH * NH;
            for (int idx = tid; idx < NH * NT; idx += NTHR) {
                int nl = idx >> 9;
                int m  = idx & (NH - 1);
                int pos = ((((nl >> 2) + (m >> 6)) & 3) << 2) | (nl & 3);
                s_wff[m * NT + pos] = gf[(size_t)(n0 + nl) * NH + m];
            }
        }
    }
    __syncthreads();

    const int wave = tid >> 6, lane = tid & 63;
    const int mseg = lane >> 3, rb = lane & 7;
    const int rt   = wave * 8 + rb;        // row in 32-tile
    const int row  = b0 + rt;
    const int m0   = mseg * 64, mg0 = mseg * 16;
    const int rot  = mseg & 3;

    // finalize constants: lanes with mseg<4 handle granule q = mseg (4 n)
    const int q = mseg;
    float wi4[4], cb4[4], al4[4], it4[4];
    if (q < 4) {
#pragma unroll
        for (int k = 0; k < 4; ++k) {
            int n = n0 + q * 4 + k;
            wi4[k] = W_in[d * NH + n];
            float cbv = b_hh[d * NH + n] + b_in[d * NH + n];
            if (d > 0) cbv += b_ff[(d - 1) * NH + n];
            cb4[k] = cbv;
            float tc = fmaxf(taus[d * NH + n], 1.0f);
            it4[k] = 1.0f / tc;
            al4[k] = 1.0f - it4[k];
        }
    }
    u64 prev = 0;

    for (int t = 0; t < TSTEPS; ++t) {
        // ---- designated polls (v6 scheme; groups of 32 slots = 2 lines) ----
        if (wave == 0) {
            if (t > 0) {
                const int* p = slots + g * 32 + (lane & 31);
                while (!__all(ld_slot(p) >= t)) __builtin_amdgcn_s_sleep(1);
            }
        } else if (wave == 1) {
            if (d > 0) {
                const int* p = slots + (g - 4) * 32 + (lane & 31);
                const int thr = t + 1;
                while (!__all(ld_slot(p) >= thr)) __builtin_amdgcn_s_sleep(1);
            }
        } else if (wave == 2) {
            if (d < DMOD - 1 && t >= RING) {
                const int* p = slots + (g + 4) * 32 + (lane & 31);
                const int thr = t - RING + 1;
                while (!__all(ld_slot(p) >= thr)) __builtin_amdgcn_s_sleep(1);
            }
        }
        __syncthreads();
        asm volatile("" ::: "memory");

        // ---- matmul: lane = (mseg, rb); 64 m x 16 n, own + ff ----
        v2f acc[8];
#pragma unroll
        for (int k = 0; k < 8; ++k) acc[k] = (v2f){0.f, 0.f};

        u64 gu[16];
        if (d > 0) {
            const u64* hg = hbq + (((size_t)(t & 3) * 12 + (g - 4)) << 12);
#pragma unroll
            for (int i = 0; i < 16; ++i) gu[i] = ld_h(hg + (size_t)(mg0 + i) * 32 + rt);
        }
        if (t == 0) {
            const float4* h4 = (const float4*)h0 + (size_t)(d * BATCH + row) * 128 + mg0;
#pragma unroll 4
            for (int i = 0; i < 16; ++i) {
                float4 hv = h4[i];
                MR4(hv.x, s_whh, m0 + i * 4 + 0)
                MR4(hv.y, s_whh, m0 + i * 4 + 1)
                MR4(hv.z, s_whh, m0 + i * 4 + 2)
                MR4(hv.w, s_whh, m0 + i * 4 + 3)
            }
        } else {
            const u64* hr = hbq + (((size_t)((t - 1) & 3) * 12 + g) << 12);
            u64 hu[16];
#pragma unroll
            for (int i = 0; i < 16; ++i) hu[i] = ld_h(hr + (size_t)(mg0 + i) * 32 + rt);
#pragma unroll 4
            for (int i = 0; i < 16; ++i) {
                u64 u = hu[i];
                MR4(bflo((u32)u),         s_whh, m0 + i * 4 + 0)
                MR4(bfhi((u32)u),         s_whh, m0 + i * 4 + 1)
                MR4(bflo((u32)(u >> 32)), s_whh, m0 + i * 4 + 2)
                MR4(bfhi((u32)(u >> 32)), s_whh, m0 + i * 4 + 3)
            }
        }
        if (d > 0) {
#pragma unroll 4
            for (int i = 0; i < 16; ++i) {
                u64 u = gu[i];
                MR4(bflo((u32)u),         s_wff, m0 + i * 4 + 0)
                MR4(bfhi((u32)u),         s_wff, m0 + i * 4 + 1)
                MR4(bflo((u32)(u >> 32)), s_wff, m0 + i * 4 + 2)
                MR4(bfhi((u32)(u >> 32)), s_wff, m0 + i * 4 + 3)
            }
        }

        // ---- in-wave butterfly over mseg (lane bits 3..5) ----
        float* af = (float*)acc;   // 16 floats
#pragma unroll
        for (int k = 0; k < 16; ++k) {
            af[k] += __shfl_xor(af[k], 8, 64);
            af[k] += __shfl_xor(af[k], 16, 64);
            af[k] += __shfl_xor(af[k], 32, 64);
        }

        // ---- finalize: every wave, lanes mseg<4 -> granule q, its 8 rows ----
        if (q < 4) {
            float xs = data[t * BATCH + row];
            float h0f, h1f, h2f, h3f;
            if (t == 0) {
                float4 v = *(const float4*)(h0 + (size_t)(d * BATCH + row) * NH
                                            + n0 + q * 4);
                h0f = v.x; h1f = v.y; h2f = v.z; h3f = v.w;
            } else {
                h0f = bflo((u32)prev);         h1f = bfhi((u32)prev);
                h2f = bflo((u32)(prev >> 32)); h3f = bfhi((u32)(prev >> 32));
            }
            float p0 = af[q * 4 + 0] + cb4[0] + xs * wi4[0];
            float p1 = af[q * 4 + 1] + cb4[1] + xs * wi4[1];
            float p2 = af[q * 4 + 2] + cb4[2] + xs * wi4[2];
            float p3 = af[q * 4 + 3] + cb4[3] + xs * wi4[3];
            float n0v = al4[0] * h0f + lrelu(p0) * it4[0];
            float n1v = al4[1] * h1f + lrelu(p1) * it4[1];
            float n2v = al4[2] * h2f + lrelu(p2) * it4[2];
            float n3v = al4[3] * h3f + lrelu(p3) * it4[3];
            u64 pk = pack4bf(n0v, n1v, n2v, n3v);
            prev = pk;
            st_h(hbq + (((size_t)(t & 3) * 12 + g) << 12)
                 + (size_t)(nt * 4 + q) * 32 + rt, pk);
            if (t == TSTEPS - 1) {
                *(float4*)(out + (size_t)(d * BATCH + row) * NH + n0 + q * 4)
                    = make_float4(n0v, n1v, n2v, n3v);
            }
        }
        __threadfence_block();   // each wave drains its h stores
        __syncthreads();         // all waves drained
        if (tid == 0) st_slot(slots + g * 32 + nt, t + 1);
    }

    // ---- readout heads (v6 pattern) ----
    if (wave == 0) {
        const int* p = slots + g * 32 + (lane & 31);
        while (!__all(ld_slot(p) >= TSTEPS)) __builtin_amdgcn_s_sleep(2);
    }
    __syncthreads();
    asm volatile("" ::: "memory");
    if (nt < CCLS && tid < BT) {
        const int c   = nt;
        const int rr  = b0 + tid;
        const u64* hf = hbq + (((size_t)3 * 12 + g) << 12);   // (511)&3 == 3
        const float4* wf = (const float4*)(W_fc + (size_t)(d * CCLS + c) * NH);
        float sacc = b_fc[d * CCLS + c];
        for (int q2 = 0; q2 < NH / 4; ++q2) {
            u64 u = ld_h(hf + (size_t)q2 * 32 + tid);
            float4 w = wf[q2];
            sacc += bflo((u32)u) * w.x + bfhi((u32)u) * w.y
                  + bflo((u32)(u >> 32)) * w.z + bfhi((u32)(u >> 32)) * w.w;
        }
        out[OUT2 + (size_t)(d * BATCH + rr) * CCLS + c] = sacc;
    }
}

extern "C" void kernel_launch(void* const* d_in, const int* in_sizes, int n_in,
                              void* d_out, int out_size, void* d_ws, size_t ws_size,
                              hipStream_t stream) {
    const float* data = (const float*)d_in[0];
    const float* h0   = (const float*)d_in[1];
    const float* W_in = (const float*)d_in[2];
    const float* b_in = (const float*)d_in[3];
    const float* W_hh = (const float*)d_in[4];
    const float* b_hh = (const float*)d_in[5];
    const float* W_ff = (const float*)d_in[6];
    const float* b_ff = (const float*)d_in[7];
    const float* taus = (const float*)d_in[8];
    const float* W_fc = (const float*)d_in[9];
    const float* b_fc = (const float*)d_in[10];

    // no init: slot poison 0xAAAAAAAA reads negative = "not done"; store-only.
    hipLaunchKernelGGL(rnn_v10, dim3(NBLK), dim3(NTHR), 0, stream,
                       data, h0, W_in, b_in, W_hh, b_hh, W_ff, b_ff,
                       taus, W_fc, b_fc, (float*)d_out, (int*)d_ws);
}

// Round 11
// 5003.881 us; speedup vs baseline: 2.4287x; 2.1249x over previous
//
#include <hip/hip_runtime.h>

// Hierarchical RNN — MFMA dataflow, v11.
// Wave = one (d, bt16, nt16) C-tile. Weights preloaded ONCE into VGPRs as
// MFMA A-fragments (bf16); h is the B-operand, read from the MALL ring slab
// in natural [b][hidden] bf16 layout. 32 mfma_f32_16x16x32_bf16 per step.
// ZERO LDS in the time loop (v6-v10 were LDS-return-path bound:
// 3072 ds_read_b128/CU/step x ~12cyc = the 15.5us plateau).
// Sync: v6 scheme — store-only flags, ring-4, lane-parallel polls, WAR slack.

#define TSTEPS 512
#define BATCH  128
#define DMOD   3
#define NH     512
#define CCLS   2
#define OUT2   (DMOD * BATCH * NH)

typedef unsigned long long u64;
typedef unsigned int u32;
typedef __attribute__((ext_vector_type(8))) short bf16x8;
typedef __attribute__((ext_vector_type(4))) float f32x4;

__device__ __forceinline__ float bflo(u32 u) { return __uint_as_float(u << 16); }
__device__ __forceinline__ float bfhi(u32 u) { return __uint_as_float(u & 0xffff0000u); }
__device__ __forceinline__ unsigned short f2bf(float x) {
    u32 u = __float_as_uint(x);
    return (unsigned short)((u + 0x7fffu + ((u >> 16) & 1u)) >> 16);
}
__device__ __forceinline__ u64 pack4bf(float a, float b, float c, float d) {
    u32 lo = (u32)f2bf(a) | ((u32)f2bf(b) << 16);
    u32 hi = (u32)f2bf(c) | ((u32)f2bf(d) << 16);
    return (u64)lo | ((u64)hi << 32);
}
__device__ __forceinline__ float lrelu(float x) { return fmaxf(x, 0.01f * x); }

__device__ __forceinline__ u64 ld_h(const u64* p) {
    return __hip_atomic_load(p, __ATOMIC_RELAXED, __HIP_MEMORY_SCOPE_AGENT);
}
__device__ __forceinline__ void st_h(u64* p, u64 v) {
    __hip_atomic_store(p, v, __ATOMIC_RELAXED, __HIP_MEMORY_SCOPE_AGENT);
}
__device__ __forceinline__ int ld_slot(const int* p) {
    return __hip_atomic_load(p, __ATOMIC_RELAXED, __HIP_MEMORY_SCOPE_AGENT);
}
__device__ __forceinline__ void st_slot(int* p, int v) {
    __hip_atomic_store(p, v, __ATOMIC_RELAXED, __HIP_MEMORY_SCOPE_AGENT);
}

__global__ __launch_bounds__(64, 1)
void rnn_mfma(const float* __restrict__ data,
              const float* __restrict__ h0,
              const float* __restrict__ W_in,
              const float* __restrict__ b_in,
              const float* __restrict__ W_hh,
              const float* __restrict__ b_hh,
              const float* __restrict__ W_ff,
              const float* __restrict__ b_ff,
              const float* __restrict__ taus,
              const float* __restrict__ W_fc,
              const float* __restrict__ b_fc,
              float* __restrict__ out,
              int* __restrict__ wsI)
{
    const int w    = blockIdx.x;        // 0..767
    const int d    = w >> 8;
    const int r    = w & 255;
    const int bt   = r >> 5;            // 0..7 (16-row b-tile)
    const int nt   = r & 31;            // 0..31 (16-col n-tile)
    const int lane = threadIdx.x;       // 0..63
    const int colb = lane & 15;         // C col = local b
    const int quad = lane >> 4;         // 0..3
    const int b    = bt * 16 + colb;
    const int n0   = nt * 16 + quad * 4;    // this lane's 4 C-rows (n)

    int* flags = wsI;                        // [24 cohorts][32]
    int* rdfl  = wsI + 1024;                 // @4096 B
    u64* slab  = (u64*)((char*)wsI + 65536); // [4][3][128 b][128] u64 (bf16 h)

    // ---- preload weights as A-fragments (A[m=lane&15][k=quad*8+j]) ----
    bf16x8 wOwn[16], wFf[16];
    {
        const int nrow = nt * 16 + colb;     // A m-index = n_out
        const float* gw = W_hh + ((size_t)d * NH + nrow) * NH;
        for (int kc = 0; kc < 16; ++kc) {
            int k0 = kc * 32 + quad * 8;
            union { unsigned short s[8]; bf16x8 v; } u;
            for (int j = 0; j < 8; ++j) {
                float x = gw[k0 + j];
                if (k0 + j == nrow) x = 0.f;   // zeroed diagonal
                u.s[j] = f2bf(x);
            }
            wOwn[kc] = u.v;
        }
        if (d > 0) {
            const float* gf = W_ff + ((size_t)(d - 1) * NH + nrow) * NH;
            for (int kc = 0; kc < 16; ++kc) {
                int k0 = kc * 32 + quad * 8;
                union { unsigned short s[8]; bf16x8 v; } u;
                for (int j = 0; j < 8; ++j) u.s[j] = f2bf(gf[k0 + j]);
                wFf[kc] = u.v;
            }
        }
    }

    // finalize constants for this lane's 4 n
    float wi4[4], cb4[4], al4[4], it4[4];
#pragma unroll
    for (int k = 0; k < 4; ++k) {
        int n = n0 + k;
        wi4[k] = W_in[d * NH + n];
        float cbv = b_hh[d * NH + n] + b_in[d * NH + n];
        if (d > 0) cbv += b_ff[(d - 1) * NH + n];
        cb4[k] = cbv;
        float tc = fmaxf(taus[d * NH + n], 1.0f);
        it4[k] = 1.0f / tc;
        al4[k] = 1.0f - it4[k];
    }

    const int coh = d * 8 + bt;
    const int* fo = flags + coh * 32 + (lane & 31);
    const int* fp = (d > 0) ? flags + (coh - 8) * 32 + (lane & 31) : fo;
    const int* ro = rdfl + coh * 32 + (lane & 31);
    const int* ru = (d < DMOD - 1) ? rdfl + (coh + 8) * 32 + (lane & 31) : ro;
    int* fmy = flags + coh * 32 + nt;
    int* rmy = rdfl + coh * 32 + nt;

    u64 prev = 0;

    for (int t = 0; t < TSTEPS; ++t) {
        // ---- dep spin: lanes 0-31 own-producers >= t, 32-63 ff >= t+1 ----
        if (t > 0 || d > 0) {
            while (1) {
                bool ok = true;
                if (lane < 32) { if (t > 0) ok = ld_slot(fo) >= t; }
                else if (d > 0) ok = (ld_slot(fp) >= t + 1);
                if (__all(ok)) break;
                __builtin_amdgcn_s_sleep(1);
            }
            asm volatile("" ::: "memory");
        }

        // ---- load B-fragments: own h(t-1), ff h_{d-1}(t) ----
        u64 hu[32], gu[32];
        if (t == 0) {
            const float* hp = h0 + ((size_t)(d * BATCH) + b) * NH + quad * 8;
#pragma unroll
            for (int kc = 0; kc < 16; ++kc) {
                float4 x0 = *(const float4*)(hp + kc * 32);
                float4 x1 = *(const float4*)(hp + kc * 32 + 4);
                hu[2 * kc]     = pack4bf(x0.x, x0.y, x0.z, x0.w);
                hu[2 * kc + 1] = pack4bf(x1.x, x1.y, x1.z, x1.w);
            }
        } else {
            const u64* hp = slab + (((size_t)((t - 1) & 3) * 3 + d) << 14)
                          + (size_t)b * 128 + quad * 2;
#pragma unroll
            for (int kc = 0; kc < 16; ++kc) {
                hu[2 * kc]     = ld_h(hp + kc * 8);
                hu[2 * kc + 1] = ld_h(hp + kc * 8 + 1);
            }
        }
        if (d > 0) {
            const u64* gp = slab + (((size_t)(t & 3) * 3 + (d - 1)) << 14)
                          + (size_t)b * 128 + quad * 2;
#pragma unroll
            for (int kc = 0; kc < 16; ++kc) {
                gu[2 * kc]     = ld_h(gp + kc * 8);
                gu[2 * kc + 1] = ld_h(gp + kc * 8 + 1);
            }
        }

        // ---- MFMA: C[m=n_out][n=b], 16 own + 16 ff, one accumulator ----
        f32x4 acc = {0.f, 0.f, 0.f, 0.f};
#pragma unroll
        for (int kc = 0; kc < 16; ++kc) {
            union { u64 q[2]; bf16x8 v; } ub;
            ub.q[0] = hu[2 * kc]; ub.q[1] = hu[2 * kc + 1];
            acc = __builtin_amdgcn_mfma_f32_16x16x32_bf16(wOwn[kc], ub.v, acc, 0, 0, 0);
        }
        if (d > 0) {
#pragma unroll
            for (int kc = 0; kc < 16; ++kc) {
                union { u64 q[2]; bf16x8 v; } ub;
                ub.q[0] = gu[2 * kc]; ub.q[1] = gu[2 * kc + 1];
                acc = __builtin_amdgcn_mfma_f32_16x16x32_bf16(wFf[kc], ub.v, acc, 0, 0, 0);
            }
        }

        __threadfence_block();                   // loads drained (vmcnt 0)
        if (lane == 0) st_slot(rmy, t);          // publish read progress

        // ---- finalize (lane-local: 4 n for its b) ----
        float xs = data[t * BATCH + b];
        float h0f, h1f, h2f, h3f;
        if (t == 0) {
            float4 v = *(const float4*)(h0 + ((size_t)(d * BATCH) + b) * NH + n0);
            h0f = v.x; h1f = v.y; h2f = v.z; h3f = v.w;
        } else {
            h0f = bflo((u32)prev);         h1f = bfhi((u32)prev);
            h2f = bflo((u32)(prev >> 32)); h3f = bfhi((u32)(prev >> 32));
        }
        float p0 = acc.x + cb4[0] + xs * wi4[0];
        float p1 = acc.y + cb4[1] + xs * wi4[1];
        float p2 = acc.z + cb4[2] + xs * wi4[2];
        float p3 = acc.w + cb4[3] + xs * wi4[3];
        float n0v = al4[0] * h0f + lrelu(p0) * it4[0];
        float n1v = al4[1] * h1f + lrelu(p1) * it4[1];
        float n2v = al4[2] * h2f + lrelu(p2) * it4[2];
        float n3v = al4[3] * h3f + lrelu(p3) * it4[3];
        u64 pk = pack4bf(n0v, n1v, n2v, n3v);
        prev = pk;

        // ---- WAR guard (ring-4 slack; normally instant) ----
        if (t >= 4) {
            while (1) {
                bool ok = true;
                if (lane < 32) ok = (ld_slot(ro) >= t - 3);
                else if (d < DMOD - 1) ok = (ld_slot(ru) >= t - 4);
                if (__all(ok)) break;
                __builtin_amdgcn_s_sleep(1);
            }
        }

        st_h(slab + (((size_t)(t & 3) * 3 + d) << 14)
             + (size_t)b * 128 + (size_t)nt * 4 + quad, pk);
        if (t == TSTEPS - 1) {
            *(float4*)(out + ((size_t)(d * BATCH) + b) * NH + n0)
                = make_float4(n0v, n1v, n2v, n3v);
        }
        __threadfence_block();                   // payload acked before flag
        if (lane == 0) st_slot(fmy, t + 1);
    }

    // ---- readout heads: waves nt==0; lane<32 -> (b = lane&15, c = lane>>4) ----
    if (nt == 0) {
        while (1) {
            bool ok = true;
            if (lane < 32) ok = (ld_slot(fo) >= TSTEPS);
            if (__all(ok)) break;
            __builtin_amdgcn_s_sleep(2);
        }
        asm volatile("" ::: "memory");
        if (lane < 32) {
            const int bb = bt * 16 + (lane & 15);
            const int c  = (lane >> 4) & 1;
            const u64* hf = slab + (((size_t)3 * 3 + d) << 14) + (size_t)bb * 128;
            const float4* wf = (const float4*)(W_fc + ((size_t)(d * CCLS) + c) * NH);
            float s = b_fc[d * CCLS + c];
            for (int q2 = 0; q2 < 128; ++q2) {
                u64 u = ld_h(hf + q2);
                float4 ww = wf[q2];
                s += bflo((u32)u) * ww.x + bfhi((u32)u) * ww.y
                   + bflo((u32)(u >> 32)) * ww.z + bfhi((u32)(u >> 32)) * ww.w;
            }
            out[OUT2 + (size_t)(d * BATCH + bb) * CCLS + c] = s;
        }
    }
}

extern "C" void kernel_launch(void* const* d_in, const int* in_sizes, int n_in,
                              void* d_out, int out_size, void* d_ws, size_t ws_size,
                              hipStream_t stream) {
    const float* data = (const float*)d_in[0];
    const float* h0   = (const float*)d_in[1];
    const float* W_in = (const float*)d_in[2];
    const float* b_in = (const float*)d_in[3];
    const float* W_hh = (const float*)d_in[4];
    const float* b_hh = (const float*)d_in[5];
    const float* W_ff = (const float*)d_in[6];
    const float* b_ff = (const float*)d_in[7];
    const float* taus = (const float*)d_in[8];
    const float* W_fc = (const float*)d_in[9];
    const float* b_fc = (const float*)d_in[10];

    // no init: flag/rdfl poison 0xAAAAAAAA reads negative = "not done".
    hipLaunchKernelGGL(rnn_mfma, dim3(768), dim3(64), 0, stream,
                       data, h0, W_in, b_in, W_hh, b_hh, W_ff, b_ff,
                       taus, W_fc, b_fc, (float*)d_out, (int*)d_ws);
}